// Round 2
// baseline (421.387 us; speedup 1.0000x reference)
//
#include <hip/hip_runtime.h>

#define TS 524288u          // 2^19
#define PRIME 2654435761u

typedef float vfloat4 __attribute__((ext_vector_type(4)));

// floor(16 * fl32(g)^l), g = 64^(1/15); fl32(g) rounds UP so the exact-integer
// levels (5,10,15) floor to 64/256/1024 under correctly-rounded powf (= numpy).
__device__ __constant__ float c_scale[16] = {
    16.f, 21.f, 27.f, 36.f, 48.f, 64.f, 84.f, 111.f,
    147.f, 194.f, 256.f, 337.f, 445.f, 588.f, 776.f, 1024.f
};

__global__ __launch_bounds__(256) void hashenc_kernel(
    const float2* __restrict__ x,
    const float2* __restrict__ tab,
    vfloat4* __restrict__ out)
{
    unsigned t  = blockIdx.x * 256u + threadIdx.x;   // [0, 8M)
    unsigned lp = t & 7u;                            // level pair id
    unsigned p  = t >> 3;                            // point id

    float2 xy = x[p];
    vfloat4 r;

    unsigned l0 = lp * 2u;
#pragma unroll
    for (int k = 0; k < 2; ++k) {
        unsigned l = l0 + (unsigned)k;
        float s = c_scale[l];

        float sx = xy.x * s;
        float sy = xy.y * s;
        float fxf = floorf(sx), fyf = floorf(sy);
        float cxf = ceilf(sx),  cyf = ceilf(sy);
        float ox = sx - fxf,    oy = sy - fyf;

        unsigned fx = (unsigned)(int)fxf, fy = (unsigned)(int)fyf;
        unsigned cx = (unsigned)(int)cxf, cy = (unsigned)(int)cyf;

        unsigned hcy = cy * PRIME;
        unsigned hfy = fy * PRIME;
        unsigned base = l << 19;

        // v0=(cx,cy) v1=(cx,fy) v2=(fx,cy) v3=(fx,fy) — per reference
        float2 f0 = tab[((cx ^ hcy) & (TS - 1u)) | base];
        float2 f1 = tab[((cx ^ hfy) & (TS - 1u)) | base];
        float2 f2 = tab[((fx ^ hcy) & (TS - 1u)) | base];
        float2 f3 = tab[((fx ^ hfy) & (TS - 1u)) | base];

        // replicate reference blend exactly (including its f2/f3 weighting)
        float wox = 1.0f - ox, woy = 1.0f - oy;
        float f03x = f0.x * ox + f3.x * wox;
        float f03y = f0.y * ox + f3.y * wox;
        float f12x = f1.x * ox + f2.x * wox;
        float f12y = f1.y * ox + f2.y * wox;
        float ex = f03x * oy + f12x * woy;
        float ey = f03y * oy + f12y * woy;

        if (k == 0) { r.x = ex; r.y = ey; }
        else        { r.z = ex; r.w = ey; }
    }

    // out vfloat4 index t == floats p*32 + lp*4 → levels (2lp, 2lp+1), coalesced.
    __builtin_nontemporal_store(r, &out[t]);
}

extern "C" void kernel_launch(void* const* d_in, const int* in_sizes, int n_in,
                              void* d_out, int out_size, void* d_ws, size_t ws_size,
                              hipStream_t stream)
{
    const float2* x   = (const float2*)d_in[0];
    const float2* tab = (const float2*)d_in[1];
    vfloat4* out = (vfloat4*)d_out;

    unsigned n_threads = (unsigned)((size_t)out_size / 4);   // 8,388,608
    unsigned n_blocks  = n_threads / 256u;                   // 32,768
    hashenc_kernel<<<n_blocks, 256, 0, stream>>>(x, tab, out);
}